// Round 1
// baseline (114.058 us; speedup 1.0000x reference)
//
#include <hip/hip_runtime.h>
#include <hip/hip_bf16.h>

#define NN 8192
#define FIN 256
#define FOUT 128

typedef __attribute__((ext_vector_type(8))) short short8;
typedef __attribute__((ext_vector_type(4))) float f32x4;
typedef unsigned short u16;

__device__ inline u16 bf16r(float v) {
  return __builtin_bit_cast(u16, __float2bfloat16(v));
}

// ---------------- h = x @ W  (fp32), e = leaky_relu(h @ a) ----------------
__global__ __launch_bounds__(256) void k_h_e(const float* __restrict__ x,
                                             const float* __restrict__ W,
                                             const float* __restrict__ a,
                                             float* __restrict__ h,
                                             float* __restrict__ e) {
  __shared__ float xs[32 * 256];
  __shared__ float ap[4][16];
  const int t = threadIdx.x;
  const int r0 = blockIdx.x * 32;

  const float4* xg = (const float4*)(x + (size_t)r0 * FIN);
  float4* xs4 = (float4*)xs;
#pragma unroll
  for (int p = 0; p < 8; ++p) xs4[p * 256 + t] = xg[p * 256 + t];
  __syncthreads();

  const int f = t & 127;
  const int half = t >> 7;
  float acc[16];
#pragma unroll
  for (int i = 0; i < 16; ++i) acc[i] = 0.f;

  const float4* xsr = (const float4*)(xs + half * 16 * 256);
  for (int k4 = 0; k4 < 64; ++k4) {
    float w0 = W[(k4 * 4 + 0) * FOUT + f];
    float w1 = W[(k4 * 4 + 1) * FOUT + f];
    float w2 = W[(k4 * 4 + 2) * FOUT + f];
    float w3 = W[(k4 * 4 + 3) * FOUT + f];
#pragma unroll
    for (int i = 0; i < 16; ++i) {
      float4 xv = xsr[i * 64 + k4];
      acc[i] = fmaf(xv.x, w0, acc[i]);
      acc[i] = fmaf(xv.y, w1, acc[i]);
      acc[i] = fmaf(xv.z, w2, acc[i]);
      acc[i] = fmaf(xv.w, w3, acc[i]);
    }
  }
#pragma unroll
  for (int i = 0; i < 16; ++i)
    h[(size_t)(r0 + half * 16 + i) * FOUT + f] = acc[i];

  const float af = a[f];
  float part[16];
#pragma unroll
  for (int i = 0; i < 16; ++i) part[i] = acc[i] * af;
#pragma unroll
  for (int i = 0; i < 16; ++i) {
#pragma unroll
    for (int off = 32; off >= 1; off >>= 1) part[i] += __shfl_xor(part[i], off);
  }
  const int wvid = t >> 6;
  if ((t & 63) == 0) {
#pragma unroll
    for (int i = 0; i < 16; ++i) ap[wvid][i] = part[i];
  }
  __syncthreads();
  if (t < 32) {
    int i = t & 15, hh = t >> 4;
    float alpha = ap[hh * 2][i] + ap[hh * 2 + 1][i];
    e[r0 + hh * 16 + i] = alpha > 0.f ? alpha : 0.2f * alpha;
  }
}

// ---------------- global max of e ----------------
__global__ __launch_bounds__(1024) void k_max(const float* __restrict__ e,
                                              float* __restrict__ M) {
  __shared__ float red[16];
  const int t = threadIdx.x;
  float m = -3.4e38f;
  for (int i = t; i < NN; i += 1024) m = fmaxf(m, e[i]);
#pragma unroll
  for (int off = 32; off >= 1; off >>= 1) m = fmaxf(m, __shfl_xor(m, off));
  if ((t & 63) == 0) red[t >> 6] = m;
  __syncthreads();
  if (t == 0) {
    float mm = red[0];
#pragma unroll
    for (int i = 1; i < 16; ++i) mm = fmaxf(mm, red[i]);
    *M = mm;
  }
}

// ---------------- w[j] = exp(e[j]-M);  gT[f][j] = bf16(w[j]*h[j][f]) ----------------
__global__ __launch_bounds__(256) void k_gw(const float* __restrict__ h,
                                            const float* __restrict__ e,
                                            const float* __restrict__ Mp,
                                            float* __restrict__ w,
                                            u16* __restrict__ gT) {
  __shared__ float wsh[64];
  __shared__ u16 gsh[64][132];  // padded row: 264B, 8B-aligned
  const int t = threadIdx.x;
  const int j0 = blockIdx.x * 64;
  const float M = *Mp;
  if (t < 64) {
    float wv = __expf(e[j0 + t] - M);
    wsh[t] = wv;
    w[j0 + t] = wv;
  }
  __syncthreads();
#pragma unroll
  for (int p = 0; p < 8; ++p) {
    int lin = p * 256 + t;
    int j = lin >> 5;
    int fc = (lin & 31) * 4;
    float4 hv = *(const float4*)(h + (size_t)(j0 + j) * FOUT + fc);
    float wv = wsh[j];
    ushort4 g4;
    g4.x = bf16r(hv.x * wv);
    g4.y = bf16r(hv.y * wv);
    g4.z = bf16r(hv.z * wv);
    g4.w = bf16r(hv.w * wv);
    *(ushort4*)&gsh[j][fc] = g4;
  }
  __syncthreads();
  const int f = t >> 1;
  const int jc = (t & 1) * 32;
  u16* dst = gT + (size_t)f * NN + j0 + jc;
#pragma unroll
  for (int q = 0; q < 8; ++q) {
    ushort4 v;
    v.x = gsh[jc + q * 4 + 0][f];
    v.y = gsh[jc + q * 4 + 1][f];
    v.z = gsh[jc + q * 4 + 2][f];
    v.w = gsh[jc + q * 4 + 3][f];
    *(ushort4*)(dst + q * 4) = v;
  }
}

// ---------------- out = (adj @ (w.h)) / (adj @ w), bf16 MFMA ----------------
// BM=32, BN=128(all), BK=64, 8 waves, double-buffered LDS, reg-prefetch.
__global__ __launch_bounds__(512) void k_gemm(const int* __restrict__ adj,
                                              const u16* __restrict__ gT,
                                              const float* __restrict__ w,
                                              float* __restrict__ out) {
  __shared__ u16 Ash[2][32 * 64];    // [row][k], XOR-swizzled, 2x4KB
  __shared__ u16 Bsh[2][128 * 64];   // [f][k],   XOR-swizzled, 2x16KB
  __shared__ float denom_sh[32];

  const int t = threadIdx.x;
  const int lane = t & 63;
  const int wvid = t >> 6;   // 0..7
  const int wr = wvid >> 2;  // row half (16 rows)
  const int wc = wvid & 3;   // col quarter (32 cols)
  const int r0 = blockIdx.x * 32;

  // staging assignment
  const int ar = t >> 4;          // 0..31 (adj row within tile)
  const int ako = (t & 15) * 4;   // k offset (int4)
  const int* adjrow = adj + (size_t)(r0 + ar) * NN + ako;
  const int bfr = t >> 3;         // 0..63 (gT row)
  const int bck = (t & 7) * 8;    // k offset (8 bf16)

  f32x4 acc0 = {0.f, 0.f, 0.f, 0.f};
  f32x4 acc1 = {0.f, 0.f, 0.f, 0.f};
  float dpart = 0.f;

  int4 av;
  float4 wq;
  short8 bb0, bb1;

  auto LOAD = [&](int kt) {
    av = *(const int4*)(adjrow + kt * 64);
    wq = *(const float4*)(w + kt * 64 + ako);
    const u16* gp = gT + (size_t)bfr * NN + kt * 64 + bck;
    bb0 = *(const short8*)gp;
    bb1 = *(const short8*)(gp + (size_t)64 * NN);
  };
  auto STORE = [&](int buf) {
    dpart += (av.x ? wq.x : 0.f) + (av.y ? wq.y : 0.f) +
             (av.z ? wq.z : 0.f) + (av.w ? wq.w : 0.f);
    ushort4 a4;
    a4.x = av.x ? (u16)0x3F80 : (u16)0;
    a4.y = av.y ? (u16)0x3F80 : (u16)0;
    a4.z = av.z ? (u16)0x3F80 : (u16)0;
    a4.w = av.w ? (u16)0x3F80 : (u16)0;
    int abyte = ar * 128 + ((ako * 2) ^ ((ar & 7) << 4));
    *(ushort4*)((char*)&Ash[buf][0] + abyte) = a4;
    int bbyte = bfr * 128 + ((bck * 2) ^ ((bfr & 7) << 4));
    *(short8*)((char*)&Bsh[buf][0] + bbyte) = bb0;
    *(short8*)((char*)&Bsh[buf][0] + bbyte + 64 * 128) = bb1;
  };
  auto COMPUTE = [&](int buf) {
    const int swz = (lane & 7) << 4;
    const int arow = wr * 16 + (lane & 15);
    const int bcol = wc * 32 + (lane & 15);
#pragma unroll
    for (int kc = 0; kc < 2; ++kc) {
      int kbyte = kc * 64 + (lane >> 4) * 16;
      short8 afr = *(const short8*)((const char*)&Ash[buf][0] + arow * 128 + (kbyte ^ swz));
      short8 b0  = *(const short8*)((const char*)&Bsh[buf][0] + bcol * 128 + (kbyte ^ swz));
      short8 b1  = *(const short8*)((const char*)&Bsh[buf][0] + (bcol + 16) * 128 + (kbyte ^ swz));
      acc0 = __builtin_amdgcn_mfma_f32_16x16x32_bf16(afr, b0, acc0, 0, 0, 0);
      acc1 = __builtin_amdgcn_mfma_f32_16x16x32_bf16(afr, b1, acc1, 0, 0, 0);
    }
  };

  LOAD(0);
  STORE(0);
  LOAD(1);
  __syncthreads();
  for (int kt = 0; kt < NN / 64; ++kt) {
    int buf = kt & 1;
    if (kt + 1 < NN / 64) STORE(buf ^ 1);
    if (kt + 2 < NN / 64) LOAD(kt + 2);
    COMPUTE(buf);
    __syncthreads();
  }

  // denominator: reduce the 16 partials per row
  dpart += __shfl_xor(dpart, 1);
  dpart += __shfl_xor(dpart, 2);
  dpart += __shfl_xor(dpart, 4);
  dpart += __shfl_xor(dpart, 8);
  if ((t & 15) == 0) denom_sh[ar] = dpart;
  __syncthreads();

#pragma unroll
  for (int q = 0; q < 4; ++q) {
    int row = wr * 16 + (lane >> 4) * 4 + q;
    float d = denom_sh[row];
    int col = wc * 32 + (lane & 15);
    out[(size_t)(r0 + row) * FOUT + col] = acc0[q] / d;
    out[(size_t)(r0 + row) * FOUT + col + 16] = acc1[q] / d;
  }
}

extern "C" void kernel_launch(void* const* d_in, const int* in_sizes, int n_in,
                              void* d_out, int out_size, void* d_ws, size_t ws_size,
                              hipStream_t stream) {
  const float* x = (const float*)d_in[0];
  const int* adj = (const int*)d_in[1];
  const float* W = (const float*)d_in[2];
  const float* a = (const float*)d_in[3];
  float* out = (float*)d_out;

  char* ws = (char*)d_ws;
  float* h = (float*)ws;                                             // 4 MB
  float* e = (float*)(ws + (size_t)4 * 1024 * 1024);                 // 32 KB
  float* wexp = (float*)(ws + (size_t)4 * 1024 * 1024 + 32 * 1024);  // 32 KB
  float* M = (float*)(ws + (size_t)4 * 1024 * 1024 + 64 * 1024);     // 4 B
  u16* gT = (u16*)(ws + (size_t)4 * 1024 * 1024 + 128 * 1024);       // 2 MB

  hipLaunchKernelGGL(k_h_e, dim3(NN / 32), dim3(256), 0, stream, x, W, a, h, e);
  hipLaunchKernelGGL(k_max, dim3(1), dim3(1024), 0, stream, e, M);
  hipLaunchKernelGGL(k_gw, dim3(NN / 64), dim3(256), 0, stream, h, e, M, wexp, gT);
  hipLaunchKernelGGL(k_gemm, dim3(NN / 32), dim3(512), 0, stream, adj, gT, wexp, out);
}

// Round 2
// 96.443 us; speedup vs baseline: 1.1827x; 1.1827x over previous
//
#include <hip/hip_runtime.h>
#include <hip/hip_bf16.h>

#define NN 8192
#define FIN 256
#define FOUT 128
#define KSPLIT 2
#define KHALF (NN / KSPLIT)

typedef __attribute__((ext_vector_type(8))) short short8;
typedef __attribute__((ext_vector_type(4))) float f32x4;
typedef unsigned short u16;

__device__ inline u16 bf16r(float v) {
  return __builtin_bit_cast(u16, __float2bfloat16(v));
}

// ---- fused: h = x@W (regs), e = leaky_relu(h@a), w = exp(e), gT = bf16(w*h)^T ----
__global__ __launch_bounds__(256) void k_prep(const float* __restrict__ x,
                                              const float* __restrict__ W,
                                              const float* __restrict__ a,
                                              float* __restrict__ wexp,
                                              u16* __restrict__ gT) {
  __shared__ float xs[32 * 256];
  __shared__ float ap[4][16];
  __shared__ float wsh[32];
  __shared__ u16 gsh[32][132];
  const int t = threadIdx.x;
  const int r0 = blockIdx.x * 32;

  const float4* xg = (const float4*)(x + (size_t)r0 * FIN);
  float4* xs4 = (float4*)xs;
#pragma unroll
  for (int p = 0; p < 8; ++p) xs4[p * 256 + t] = xg[p * 256 + t];
  __syncthreads();

  const int f = t & 127;
  const int half = t >> 7;
  float acc[16];
#pragma unroll
  for (int i = 0; i < 16; ++i) acc[i] = 0.f;

  const float4* xsr = (const float4*)(xs + half * 16 * 256);
  for (int k4 = 0; k4 < 64; ++k4) {
    float w0 = W[(k4 * 4 + 0) * FOUT + f];
    float w1 = W[(k4 * 4 + 1) * FOUT + f];
    float w2 = W[(k4 * 4 + 2) * FOUT + f];
    float w3 = W[(k4 * 4 + 3) * FOUT + f];
#pragma unroll
    for (int i = 0; i < 16; ++i) {
      float4 xv = xsr[i * 64 + k4];
      acc[i] = fmaf(xv.x, w0, acc[i]);
      acc[i] = fmaf(xv.y, w1, acc[i]);
      acc[i] = fmaf(xv.z, w2, acc[i]);
      acc[i] = fmaf(xv.w, w3, acc[i]);
    }
  }

  // alpha_j = h_j . a  (per-row dot), via per-wave shuffle reduce over f
  const float af = a[f];
  float part[16];
#pragma unroll
  for (int i = 0; i < 16; ++i) part[i] = acc[i] * af;
#pragma unroll
  for (int i = 0; i < 16; ++i) {
#pragma unroll
    for (int off = 32; off >= 1; off >>= 1) part[i] += __shfl_xor(part[i], off);
  }
  const int wvid = t >> 6;
  if ((t & 63) == 0) {
#pragma unroll
    for (int i = 0; i < 16; ++i) ap[wvid][i] = part[i];
  }
  __syncthreads();
  if (t < 32) {
    int i = t & 15, hh = t >> 4;
    float alpha = ap[hh * 2][i] + ap[hh * 2 + 1][i];
    float ee = alpha > 0.f ? alpha : 0.2f * alpha;
    float wv = __expf(fminf(ee, 80.f));  // softmax shift-invariance: no global max needed
    wsh[t] = wv;
    wexp[r0 + t] = wv;
  }
  __syncthreads();

  // g[row][f] = bf16(w[row] * h[row][f]) into LDS
#pragma unroll
  for (int i = 0; i < 16; ++i) {
    int row = half * 16 + i;
    gsh[row][f] = bf16r(acc[i] * wsh[row]);
  }
  __syncthreads();

  // transposed write: gT[f][r0 + j]
  const int ff = t >> 1;
  const int jc = (t & 1) * 16;
  u16* dst = gT + (size_t)ff * NN + r0 + jc;
#pragma unroll
  for (int q = 0; q < 4; ++q) {
    ushort4 v;
    v.x = gsh[jc + q * 4 + 0][ff];
    v.y = gsh[jc + q * 4 + 1][ff];
    v.z = gsh[jc + q * 4 + 2][ff];
    v.w = gsh[jc + q * 4 + 3][ff];
    *(ushort4*)(dst + q * 4) = v;
  }
}

// ---- partial: numer[ks] = adj[:, ksrange] @ g[ksrange], denom[ks] = adj @ w ----
__global__ __launch_bounds__(512, 4) void k_gemm(const int* __restrict__ adj,
                                                 const u16* __restrict__ gT,
                                                 const float* __restrict__ w,
                                                 float* __restrict__ numer,
                                                 float* __restrict__ denom) {
  __shared__ u16 Ash[2][32 * 64];    // [row][k], XOR-swizzled
  __shared__ u16 Bsh[2][128 * 64];   // [f][k],   XOR-swizzled
  __shared__ float denom_sh[32];

  const int t = threadIdx.x;
  const int lane = t & 63;
  const int wvid = t >> 6;
  const int wr = wvid >> 2;
  const int wc = wvid & 3;
  const int r0 = blockIdx.x * 32;
  const int ks = blockIdx.y;
  const size_t kbase = (size_t)ks * KHALF;

  const int ar = t >> 4;
  const int ako = (t & 15) * 4;
  const int* adjrow = adj + (size_t)(r0 + ar) * NN + kbase + ako;
  const float* wp = w + kbase + ako;
  const int bfr = t >> 3;
  const int bck = (t & 7) * 8;
  const u16* gTb = gT + kbase + bck;

  f32x4 acc0 = {0.f, 0.f, 0.f, 0.f};
  f32x4 acc1 = {0.f, 0.f, 0.f, 0.f};
  float dpart = 0.f;

  int4 av;
  float4 wq;
  short8 bb0, bb1;

  auto LOAD = [&](int kt) {
    av = *(const int4*)(adjrow + kt * 64);
    wq = *(const float4*)(wp + kt * 64);
    const u16* gp = gTb + (size_t)bfr * NN + kt * 64;
    bb0 = *(const short8*)gp;
    bb1 = *(const short8*)(gp + (size_t)64 * NN);
  };
  auto STORE = [&](int buf) {
    dpart += (av.x ? wq.x : 0.f) + (av.y ? wq.y : 0.f) +
             (av.z ? wq.z : 0.f) + (av.w ? wq.w : 0.f);
    ushort4 a4;
    a4.x = av.x ? (u16)0x3F80 : (u16)0;
    a4.y = av.y ? (u16)0x3F80 : (u16)0;
    a4.z = av.z ? (u16)0x3F80 : (u16)0;
    a4.w = av.w ? (u16)0x3F80 : (u16)0;
    int abyte = ar * 128 + ((ako * 2) ^ ((ar & 7) << 4));
    *(ushort4*)((char*)&Ash[buf][0] + abyte) = a4;
    int bbyte = bfr * 128 + ((bck * 2) ^ ((bfr & 7) << 4));
    *(short8*)((char*)&Bsh[buf][0] + bbyte) = bb0;
    *(short8*)((char*)&Bsh[buf][0] + bbyte + 64 * 128) = bb1;
  };
  auto COMPUTE = [&](int buf) {
    const int swz = (lane & 7) << 4;
    const int arow = wr * 16 + (lane & 15);
    const int bcol = wc * 32 + (lane & 15);
#pragma unroll
    for (int kc = 0; kc < 2; ++kc) {
      int kbyte = kc * 64 + (lane >> 4) * 16;
      short8 afr = *(const short8*)((const char*)&Ash[buf][0] + arow * 128 + (kbyte ^ swz));
      short8 b0  = *(const short8*)((const char*)&Bsh[buf][0] + bcol * 128 + (kbyte ^ swz));
      short8 b1  = *(const short8*)((const char*)&Bsh[buf][0] + (bcol + 16) * 128 + (kbyte ^ swz));
      acc0 = __builtin_amdgcn_mfma_f32_16x16x32_bf16(afr, b0, acc0, 0, 0, 0);
      acc1 = __builtin_amdgcn_mfma_f32_16x16x32_bf16(afr, b1, acc1, 0, 0, 0);
    }
  };

  const int NT = KHALF / 64;  // 64 tiles
  LOAD(0);
  STORE(0);
  LOAD(1);
  __syncthreads();
  for (int kt = 0; kt < NT; ++kt) {
    int buf = kt & 1;
    if (kt + 1 < NT) STORE(buf ^ 1);
    if (kt + 2 < NT) LOAD(kt + 2);
    COMPUTE(buf);
    __syncthreads();
  }

  dpart += __shfl_xor(dpart, 1);
  dpart += __shfl_xor(dpart, 2);
  dpart += __shfl_xor(dpart, 4);
  dpart += __shfl_xor(dpart, 8);
  if ((t & 15) == 0) denom_sh[ar] = dpart;
  __syncthreads();

#pragma unroll
  for (int q = 0; q < 4; ++q) {
    int row = wr * 16 + (lane >> 4) * 4 + q;
    int col = wc * 32 + (lane & 15);
    float* np = numer + ((size_t)ks * NN + r0 + row) * FOUT + col;
    np[0] = acc0[q];
    np[16] = acc1[q];
  }
  if (t < 32) denom[(size_t)ks * NN + r0 + t] = denom_sh[t];
}

// ---- out = (n0 + n1) / (d0 + d1) ----
__global__ __launch_bounds__(256) void k_comb(const float* __restrict__ numer,
                                              const float* __restrict__ denom,
                                              float* __restrict__ out) {
  const int idx = blockIdx.x * 256 + threadIdx.x;  // 0 .. 256K-1, 4 floats each
  const int row = idx >> 5;
  const int fc = (idx & 31) * 4;
  float4 n0 = *(const float4*)(numer + (size_t)row * FOUT + fc);
  float4 n1 = *(const float4*)(numer + (size_t)(NN + row) * FOUT + fc);
  float d = denom[row] + denom[NN + row];
  float inv = 1.0f / d;
  float4 o;
  o.x = (n0.x + n1.x) * inv;
  o.y = (n0.y + n1.y) * inv;
  o.z = (n0.z + n1.z) * inv;
  o.w = (n0.w + n1.w) * inv;
  *(float4*)(out + (size_t)row * FOUT + fc) = o;
}

extern "C" void kernel_launch(void* const* d_in, const int* in_sizes, int n_in,
                              void* d_out, int out_size, void* d_ws, size_t ws_size,
                              hipStream_t stream) {
  const float* x = (const float*)d_in[0];
  const int* adj = (const int*)d_in[1];
  const float* W = (const float*)d_in[2];
  const float* a = (const float*)d_in[3];
  float* out = (float*)d_out;

  char* ws = (char*)d_ws;
  float* wexp = (float*)ws;                                   // 32 KB
  u16* gT = (u16*)(ws + 64 * 1024);                           // 2 MB
  float* numer = (float*)(ws + 4 * 1024 * 1024);              // 8 MB (2 x 8192 x 128)
  float* denom = (float*)(ws + 12 * 1024 * 1024);             // 64 KB (2 x 8192)

  hipLaunchKernelGGL(k_prep, dim3(NN / 32), dim3(256), 0, stream, x, W, a, wexp, gT);
  hipLaunchKernelGGL(k_gemm, dim3(NN / 32, KSPLIT), dim3(512), 0, stream, adj, gT, wexp,
                     numer, denom);
  hipLaunchKernelGGL(k_comb, dim3((NN * FOUT / 4) / 256), dim3(256), 0, stream, numer,
                     denom, out);
}